// Round 6
// baseline (1187.051 us; speedup 1.0000x reference)
//
#include <hip/hip_runtime.h>
#include <hip/hip_bf16.h>
#include <stdint.h>
#include <stdio.h>

#define T_SEQ 4096
#define C_ST  1024
#define K3    3072
#define NB    4
#define NCHUNK 64
#define CHUNK  64

typedef __bf16 bf16x8_t __attribute__((ext_vector_type(8)));
typedef float f32x4_t __attribute__((ext_vector_type(4)));
typedef unsigned short u16x8 __attribute__((ext_vector_type(8)));
typedef unsigned short u16x4 __attribute__((ext_vector_type(4)));
typedef __attribute__((address_space(1))) unsigned int as1u32;
typedef __attribute__((address_space(3))) unsigned int as3u32;

__device__ __forceinline__ unsigned short bfbits(float f) {
  __hip_bfloat16 h = __float2bfloat16(f);
  return *reinterpret_cast<unsigned short*>(&h);
}
__device__ __forceinline__ float bf2f(unsigned short u) {
  __hip_bfloat16 h;
  *reinterpret_cast<unsigned short*>(&h) = u;
  return __bfloat162float(h);
}
__device__ __forceinline__ float phi_f(float x) {
  // silu(x) + 1
  return x / (1.0f + __expf(-x)) + 1.0f;
}

// ---------------------------------------------------------------------------
// Weight prep: W (1024x1024 f32, row-major) -> dst rows of K3=3072 bf16:
// [Wh | Wh | Wl]  (pairs with activations stored [ah | al | ah])
// grid (1024, 4): y=0 Wq, 1 Wk, 2 Wv -> W3 rows y*1024+r ; y=3 Wo -> Wo3 row r
// ---------------------------------------------------------------------------
__global__ __launch_bounds__(256) void conv_w_kernel(
    const float* __restrict__ Wq, const float* __restrict__ Wk,
    const float* __restrict__ Wv, const float* __restrict__ Wo,
    unsigned short* __restrict__ W3, unsigned short* __restrict__ Wo3) {
  int r = blockIdx.x;
  int which = blockIdx.y;
  const float* src = (which == 0) ? Wq : (which == 1) ? Wk : (which == 2) ? Wv : Wo;
  unsigned short* dst = (which < 3) ? (W3 + (size_t)(which * 1024 + r) * K3)
                                    : (Wo3 + (size_t)r * K3);
  int c4 = threadIdx.x * 4;
  float4 v = *reinterpret_cast<const float4*>(&src[(size_t)r * 1024 + c4]);
  float fe[4] = {v.x, v.y, v.z, v.w};
  u16x4 hh, ll;
#pragma unroll
  for (int e = 0; e < 4; ++e) {
    unsigned short hb = bfbits(fe[e]);
    hh[e] = hb;
    ll[e] = bfbits(fe[e] - bf2f(hb));
  }
  *reinterpret_cast<u16x4*>(&dst[c4])        = hh;
  *reinterpret_cast<u16x4*>(&dst[1024 + c4]) = hh;
  *reinterpret_cast<u16x4*>(&dst[2048 + c4]) = ll;
}

// ---------------------------------------------------------------------------
// x prep (one batch): x_b (C, T) f32 -> xT3_b (T, 3C) bf16 [xh | xl | xh]
// grid (T/64, C/64), 256 threads, 64x64 LDS tile
// ---------------------------------------------------------------------------
__global__ __launch_bounds__(256) void conv_x_kernel(
    const float* __restrict__ xb_, unsigned short* __restrict__ xT3) {
  __shared__ float tile[64][65];
  int c0 = blockIdx.y * 64, t0 = blockIdx.x * 64;
  const float* xb = xb_ + (size_t)c0 * T_SEQ + t0;
  int tid = threadIdx.x;
#pragma unroll
  for (int p = 0; p < 4; ++p) {
    int idx = tid + p * 256;
    int r = idx >> 4, q4 = (idx & 15) * 4;
    float4 v = *reinterpret_cast<const float4*>(&xb[(size_t)r * T_SEQ + q4]);
    tile[r][q4 + 0] = v.x; tile[r][q4 + 1] = v.y;
    tile[r][q4 + 2] = v.z; tile[r][q4 + 3] = v.w;
  }
  __syncthreads();
  int r = tid >> 2, q = (tid & 3) * 16;
  u16x8 h0, h1, l0, l1;
#pragma unroll
  for (int j = 0; j < 8; ++j) {
    float f = tile[q + j][r];
    unsigned short hb = bfbits(f);
    h0[j] = hb; l0[j] = bfbits(f - bf2f(hb));
  }
#pragma unroll
  for (int j = 0; j < 8; ++j) {
    float f = tile[q + 8 + j][r];
    unsigned short hb = bfbits(f);
    h1[j] = hb; l1[j] = bfbits(f - bf2f(hb));
  }
  unsigned short* dst = xT3 + ((size_t)(t0 + r)) * K3 + c0 + q;
  *reinterpret_cast<u16x8*>(dst)         = h0;
  *reinterpret_cast<u16x8*>(dst + 8)     = h1;
  *reinterpret_cast<u16x8*>(dst + 1024)  = l0;
  *reinterpret_cast<u16x8*>(dst + 1032)  = l1;
  *reinterpret_cast<u16x8*>(dst + 2048)  = h0;
  *reinterpret_cast<u16x8*>(dst + 2056)  = h1;
}

// ---------------------------------------------------------------------------
// gemm_bt: C[m][n] = sum_k A[m][k]*B[n][k]  (+ biasM[m] if given)
// A (M,K) bf16 row-major, B (N,K) bf16 row-major, C (M,N) f32 row-major.
// 128x128 tile, BK=32, 4 waves (2x2), 16x16x32 bf16 MFMA, global_load_lds w16.
// grid (N/128, M/128)
// ---------------------------------------------------------------------------
__global__ __launch_bounds__(256) void gemm_bt_kernel(
    const unsigned short* __restrict__ A, const unsigned short* __restrict__ B,
    float* __restrict__ C, const float* __restrict__ biasM,
    int M, int N, int K) {
  __shared__ unsigned short As[128 * 32];
  __shared__ unsigned short Bs[128 * 32];
  int m0 = blockIdx.y * 128, n0 = blockIdx.x * 128;
  int tid = threadIdx.x, lane = tid & 63, wid = tid >> 6;
  int wr = wid >> 1, wc = wid & 1;
  int l16 = lane & 15, l4 = lane >> 4;
  f32x4_t acc[4][4] = {};

  for (int k0 = 0; k0 < K; k0 += 32) {
    __syncthreads();
#pragma unroll
    for (int s = 0; s < 2; ++s) {
      int chunk = wid * 2 + s;
      int flat = chunk * 1024 + lane * 16;  // byte offset within 8KB tile
      int row = flat >> 6;                  // 64 B per row (32 bf16)
      int cole = (flat & 63) >> 1;          // element offset in k
      const unsigned short* ga = A + (size_t)(m0 + row) * K + k0 + cole;
      const unsigned short* gb = B + (size_t)(n0 + row) * K + k0 + cole;
      __builtin_amdgcn_global_load_lds((as1u32*)ga, (as3u32*)(As + chunk * 512), 16, 0, 0);
      __builtin_amdgcn_global_load_lds((as1u32*)gb, (as3u32*)(Bs + chunk * 512), 16, 0, 0);
    }
    __syncthreads();
    bf16x8_t af[4], bfr[4];
#pragma unroll
    for (int m = 0; m < 4; ++m)
      af[m] = *reinterpret_cast<const bf16x8_t*>(&As[(wr * 64 + m * 16 + l16) * 32 + l4 * 8]);
#pragma unroll
    for (int n = 0; n < 4; ++n)
      bfr[n] = *reinterpret_cast<const bf16x8_t*>(&Bs[(wc * 64 + n * 16 + l16) * 32 + l4 * 8]);
#pragma unroll
    for (int m = 0; m < 4; ++m)
#pragma unroll
      for (int n = 0; n < 4; ++n)
        acc[m][n] = __builtin_amdgcn_mfma_f32_16x16x32_bf16(af[m], bfr[n], acc[m][n], 0, 0, 0);
  }

#pragma unroll
  for (int m = 0; m < 4; ++m) {
#pragma unroll
    for (int n = 0; n < 4; ++n) {
      int row = m0 + wr * 64 + m * 16 + l4 * 4;
      int col = n0 + wc * 64 + n * 16 + l16;
#pragma unroll
      for (int j = 0; j < 4; ++j) {
        float val = acc[m][n][j];
        if (biasM) val += biasM[row + j];
        C[(size_t)(row + j) * N + col] = val;
      }
    }
  }
}

// ---------------------------------------------------------------------------
// Scan phase A (one batch): per-chunk totals of phi_k and phi_k*v
// grid (NCHUNK, H=16), 64 threads (one per d)
// ---------------------------------------------------------------------------
__global__ void scan_a_kernel(const float* __restrict__ qkvT,
                              const float* __restrict__ bv,
                              float* __restrict__ partK, float* __restrict__ partKV) {
  int d = threadIdx.x;
  int ch = blockIdx.x, h = blockIdx.y;
  int c = h * 64 + d;
  float bvc = bv[c];
  const float* base = qkvT + (size_t)ch * CHUNK * K3;
  float sk = 0.f, skv = 0.f;
  for (int tt = 0; tt < CHUNK; ++tt) {
    const float* row = base + (size_t)tt * K3;
    float kv = row[1024 + c];
    float vv = row[2048 + c] + bvc;
    float pk = phi_f(kv);
    sk += pk; skv += pk * vv;
  }
  size_t pidx = ((size_t)h * NCHUNK + ch) * 64 + d;
  partK[pidx] = sk;
  partKV[pidx] = skv;
}

// Phase B: exclusive prefix over chunks. grid (16 H), 64 threads.
__global__ void scan_b_kernel(float* __restrict__ partK, float* __restrict__ partKV) {
  int d = threadIdx.x;
  int h = blockIdx.x;
  size_t base = (size_t)h * NCHUNK * 64 + d;
  float rk = 0.f, rkv = 0.f;
  for (int ch = 0; ch < NCHUNK; ++ch) {
    size_t i = base + (size_t)ch * 64;
    float tk = partK[i], tkv = partKV[i];
    partK[i] = rk; partKV[i] = rkv;
    rk += tk; rkv += tkv;
  }
}

// Phase C: emit attention output, split hi/lo bf16, t-major [oh | ol | oh]
// grid (NCHUNK, 16), 64 threads
__global__ void scan_c_kernel(const float* __restrict__ qkvT,
                              const float* __restrict__ bq, const float* __restrict__ bv,
                              const float* __restrict__ partK, const float* __restrict__ partKV,
                              unsigned short* __restrict__ outT3) {
  int d = threadIdx.x;
  int ch = blockIdx.x, h = blockIdx.y;
  int c = h * 64 + d;
  size_t pidx = ((size_t)h * NCHUNK + ch) * 64 + d;
  float sk = partK[pidx], skv = partKV[pidx];
  float bqc = bq[c], bvc = bv[c];
  const float* base = qkvT + (size_t)ch * CHUNK * K3;
  unsigned short* obase = outT3 + (size_t)ch * CHUNK * K3;
  for (int tt = 0; tt < CHUNK; ++tt) {
    const float* row = base + (size_t)tt * K3;
    float qv = row[c] + bqc;
    float kv = row[1024 + c];
    float vv = row[2048 + c] + bvc;
    float pq = phi_f(qv), pk = phi_f(kv);
    sk += pk; skv += pk * vv;
    float dp = pq * sk;
#pragma unroll
    for (int off = 32; off > 0; off >>= 1) dp += __shfl_xor(dp, off);
    float den = dp + 1e-6f;
    float o = pq * skv / den * 0.125f;  // 1/sqrt(64)
    unsigned short oh = bfbits(o);
    unsigned short ol = bfbits(o - bf2f(oh));
    unsigned short* orow = obase + (size_t)tt * K3;
    orow[c] = oh; orow[1024 + c] = ol; orow[2048 + c] = oh;
  }
}

// ---------------------------------------------------------------------------
extern "C" void kernel_launch(void* const* d_in, const int* in_sizes, int n_in,
                              void* d_out, int out_size, void* d_ws, size_t ws_size,
                              hipStream_t stream) {
  const float* x  = (const float*)d_in[0];
  const float* Wq = (const float*)d_in[1];
  const float* bq = (const float*)d_in[2];
  const float* Wk = (const float*)d_in[3];
  const float* Wv = (const float*)d_in[4];
  const float* bv = (const float*)d_in[5];
  const float* Wo = (const float*)d_in[6];
  const float* bo = (const float*)d_in[7];
  float* out = (float*)d_out;

  // Per-batch workspace layout (bytes):
  //   W3     @ 0           : 3072*3072*2 = 18,874,368
  //   Wo3    @ 18,874,368  : 1024*3072*2 =  6,291,456
  //   xT3_b  @ 25,165,824  : 4096*3072*2 = 25,165,824
  //   qkvT_b @ 50,331,648  : 4096*3072*4 = 50,331,648
  //   partK  @ 100,663,296 : 16*64*64*4  =    262,144
  //   partKV @ 100,925,440 : 16*64*64*4  =    262,144   (end 101,187,584)
  const size_t REQUIRED = 101187584;
  fprintf(stderr, "kernel_launch: ws_size=%zu required=%zu\n", ws_size, REQUIRED);
  if (ws_size < REQUIRED) return;  // clean failure instead of device fault

  char* w = (char*)d_ws;
  unsigned short* W3     = (unsigned short*)(w);
  unsigned short* Wo3    = (unsigned short*)(w + 18874368);
  unsigned short* xT3b   = (unsigned short*)(w + 25165824);
  float*          qkvTb  = (float*)(w + 50331648);
  float*          partK  = (float*)(w + 100663296);
  float*          partKV = (float*)(w + 100925440);

  // 1) weight prep (once)
  conv_w_kernel<<<dim3(1024, 4), 256, 0, stream>>>(Wq, Wk, Wv, Wo, W3, Wo3);

  for (int b = 0; b < NB; ++b) {
    const float* xb = x + (size_t)b * C_ST * T_SEQ;
    float* outb = out + (size_t)b * C_ST * T_SEQ;
    // 2) x transpose + split (batch b)
    conv_x_kernel<<<dim3(T_SEQ / 64, C_ST / 64), 256, 0, stream>>>(xb, xT3b);
    // 3) fused QKV GEMM: qkvTb[t][j] = sum_k xT3b[t][k] * W3[j][k]
    gemm_bt_kernel<<<dim3(K3 / 128, T_SEQ / 128), 256, 0, stream>>>(
        xT3b, W3, qkvTb, nullptr, T_SEQ, K3, K3);
    // 4) chunked scan (batch b); scan_c overwrites xT3b with attention output
    scan_a_kernel<<<dim3(NCHUNK, 16), 64, 0, stream>>>(qkvTb, bv, partK, partKV);
    scan_b_kernel<<<dim3(16), 64, 0, stream>>>(partK, partKV);
    scan_c_kernel<<<dim3(NCHUNK, 16), 64, 0, stream>>>(qkvTb, bq, bv, partK, partKV, xT3b);
    // 5) output GEMM: outb[o][t] = bo[o] + sum_k Wo3[o][k] * xT3b[t][k]
    gemm_bt_kernel<<<dim3(T_SEQ / 128, C_ST / 128), 256, 0, stream>>>(
        Wo3, xT3b, outb, bo, C_ST, T_SEQ, K3);
  }
}